// Round 7
// baseline (81.914 us; speedup 1.0000x reference)
//
#include <hip/hip_runtime.h>
#include <hip/hip_bf16.h>
#include <math.h>
#include <stdint.h>

// Problem constants
#define NCH   8
#define DNX   128
#define DNY   128
#define KPTS  16384

typedef __attribute__((ext_vector_type(8)))  short bf16x8;   // MFMA A/B frag (8 bf16)
typedef __attribute__((ext_vector_type(16))) float f32x16;   // 32x32 MFMA C/D frag

typedef const __attribute__((address_space(1))) unsigned int* gp_t;
typedef __attribute__((address_space(3))) unsigned int* lp_t;

// pack two fp32 -> one uint32 of two bf16 (RNE) via v_cvt_pk_bf16_f32
__device__ __forceinline__ uint32_t pkbf(float lo, float hi) {
    union { __hip_bfloat162 h; uint32_t u; } v;
    v.h = __float22bfloat162_rn(make_float2(lo, hi));
    return v.u;
}

// ---------------------------------------------------------------------------
// Prep (UNCHANGED): img (fp32 planar re/im) -> B_pre (bf16, per-channel 64KB
// image in the LDS layout). Logical B[x][col], col = 2y+s (s=0:re, 1:im).
// Address: (256*col + 64*t4 + 16*q) ^ (16*(col&7)), x = 32*t4 + 8*q + j.
// ---------------------------------------------------------------------------
__global__ __launch_bounds__(256) void prep_kernel(
    const float* __restrict__ img_real,
    const float* __restrict__ img_imag,
    unsigned short* __restrict__ B_pre)
{
    int tid = blockIdx.x * 256 + threadIdx.x;   // 32768 threads total
    int y  = tid & 127;
    int xc = (tid >> 7) & 15;                   // which 8-x chunk
    int s  = (tid >> 11) & 1;
    int c  = tid >> 12;
    int t4 = xc >> 2, q = xc & 3;
    int x0 = 32 * t4 + 8 * q;
    const float* src = (s ? img_imag : img_real) + c * (DNX * DNY) + y;
    float f[8];
    #pragma unroll
    for (int j = 0; j < 8; ++j) f[j] = src[(x0 + j) * DNY];
    int col  = 2 * y + s;
    int dest = (256 * col + 64 * t4 + 16 * q) ^ (16 * (col & 7));
    uint4 val;
    val.x = pkbf(f[0], f[1]);
    val.y = pkbf(f[2], f[3]);
    val.z = pkbf(f[4], f[5]);
    val.w = pkbf(f[6], f[7]);
    *(uint4*)((char*)B_pre + (size_t)c * 65536 + dest) = val;
}

// ---------------------------------------------------------------------------
// Main, round-7: 32x32x16 MFMA with TRANSPOSED operand roles.
// Evidence: r0-r6 invariant at ~80us total (main ~30us) across all
// scheduling/occupancy knobs; per-SIMD demand budget (MFMA 8.3us + VALU 7us
// + LDS 10.2us) matches the serial sum -> shrink demands, don't reschedule.
//
//  * A = img tile (32 ycols x 16 x) from LDS; B = per-k phase (regs);
//    D[ycol][k] via mfma_f32_32x32x16_bf16. One A-read feeds cos AND sin
//    MFMAs; MFMA instr count halves at the faster 32x32 rate; ds_reads per
//    k halve (64 reads / 32 k / wave).
//  * C layout (guide, verified): col=lane&31 (one k per lane!), rows =
//    (reg&3)+8*(reg>>2)+4*hi = 16 ycols = 8 y x {re,im}. Stage-2 is fully
//    lane-local scalar math (no parity trick, no DPP); epilogue is one
//    shfl_xor(32).
//  * A/B frag layout (extrapolated from session-verified 16x16x32 pattern):
//    row/col = lane&31, k = 8*(lane>>5)+j -> same "8 consecutive x at fixed
//    col" shape -> B_pre layout + swizzle unchanged; XOR folds into 4
//    per-lane base pointers B0..B3 with imm offsets 8192*ct + 128*P.
//  * x split into 2 passes (x 0..63, 64..127): F/G accumulation is linear in
//    x so partial sums are exact; keeps phase frags at 32 VGPR; rotors
//    re-inited per pass (cheap) -> peak ~108 VGPR, fits (512,2) cap=128.
//  * block = 8 waves x 32 k = 256 k, one channel; grid (64,8) = 512 blocks
//    -> ALL resident (2/CU, 16 waves/CU, 4 waves/SIMD), single round.
// ---------------------------------------------------------------------------
__global__ __launch_bounds__(512, 2) void nudft_mfma_kernel(
    const float* __restrict__ trj,
    const unsigned short* __restrict__ B_pre,
    float* __restrict__ out)
{
    __shared__ __align__(16) unsigned short Bl[32768];   // 64 KB: whole channel

    const int t    = threadIdx.x;     // 0..511
    const int w    = t >> 6;          // wave 0..7
    const int lane = t & 63;
    const int l31  = lane & 31;       // this lane's k within the wave; C col
    const int hi   = lane >> 5;       // K-split half (A/B) / row +4 (C)
    const int kb   = blockIdx.x;      // 0..63
    const int c    = blockIdx.y;      // 0..7 (channel)
    const int k0w  = kb * 256 + w * 32;
    const int k    = k0w + l31;       // this lane's k-point

    // ---- trj load: one (tx,ty) per lane, coalesced
    const float trjx = trj[2 * k + 0];
    const float ty   = trj[2 * k + 1];

    // ---- stage the whole 64KB channel image: 8 x 16B per thread
    {
        const char* g = (const char*)B_pre + ((size_t)c << 16) + (t << 4);
        char* l = (char*)&Bl[0] + (t << 4);
        #pragma unroll
        for (int i = 0; i < 8; ++i)
            __builtin_amdgcn_global_load_lds(
                (gp_t)(const void*)(g + (i << 13)),
                (lp_t)(void*)(l + (i << 13)), 16, 0, 0);
    }
    __builtin_amdgcn_sched_barrier(0);   // keep DMA issue ahead of trig setup

    // ---- shared rotation constants
    const float d1 = -trjx * (1.0f / 64.0f);       // pi-units per +1 x
    float s1, c1;   sincospif(d1, &s1, &c1);
    float s16, c16; sincospif(16.0f * d1, &s16, &c16);
    float rdi, rdr; sincospif(-ty * 0.25f, &rdi, &rdr);   // y += 16 rotor

    // ---- per-lane LDS A-frag bases. addr(ct,xk) for ycol = 32ct + l31,
    // x-chunk (2xk+hi):  256*ycol + 16*((2xk+hi) ^ (ycol&7))
    //   = [256*l31 + 16*(hi^(s7&1)) + 32*((xk&3)^u)] + 8192*ct + 128*(xk>>2)
    // with s7 = lane&7 (== ycol&7), u = s7>>1.
    const int s7 = lane & 7;
    const int u  = s7 >> 1;
    const int v  = hi ^ (s7 & 1);
    const char* baseA = (const char*)&Bl[0] + 256 * l31 + 16 * v;
    const char* B0 = baseA + 32 * (0 ^ u);
    const char* B1 = baseA + 32 * (1 ^ u);
    const char* B2 = baseA + 32 * (2 ^ u);
    const char* B3 = baseA + 32 * (3 ^ u);

    float ore = 0.f, oim = 0.f;      // ksp(c,k) accumulator (lane-local)
    const f32x16 ZER16 = {0.f,0.f,0.f,0.f,0.f,0.f,0.f,0.f,
                          0.f,0.f,0.f,0.f,0.f,0.f,0.f,0.f};

    __syncthreads();   // DMA drained; the ONLY barrier in the kernel

    #pragma unroll
    for (int P = 0; P < 2; ++P) {            // x-halves: x in [64P, 64P+64)
        // ---- phase B-frags for this x-half: lane's x = 64P + 16*xk + 8*hi + j
        // Px = cis(pi * d1 * (x-64)) stored as (pxr = cos ax, pxi = -sin ax)
        bf16x8 pxr[4], pxi[4];
        {
            float ps, pc;
            sincospif(d1 * (float)(64 * P + 8 * hi - 64), &ps, &pc);
            #pragma unroll
            for (int xk = 0; xk < 4; ++xk) {
                float qc = pc, qs = ps;
                float fc[8], fs[8];
                #pragma unroll
                for (int j = 0; j < 8; ++j) {
                    fc[j] = qc; fs[j] = qs;
                    if (j < 7) {
                        float tq = qc * c1 - qs * s1;
                        qs = fmaf(qc, s1, qs * c1);
                        qc = tq;
                    }
                }
                uint32_t* pr = (uint32_t*)&pxr[xk];
                uint32_t* pi = (uint32_t*)&pxi[xk];
                #pragma unroll
                for (int p = 0; p < 4; ++p) {
                    pr[p] = pkbf(fc[2 * p], fc[2 * p + 1]);
                    pi[p] = pkbf(fs[2 * p], fs[2 * p + 1]);
                }
                if (xk < 3) {
                    float tp = pc * c16 - ps * s16;
                    ps = fmaf(pc, s16, ps * c16);
                    pc = tp;
                }
            }
        }

        // ---- stage-2 rotors (re-init per pass): p = 2q+j <-> y_local =
        // 4q + 2hi + j; (cb,sb) = cis(-pi * ty * (y-64)/64) = Py
        float cb[8], sb[8];
        {
            float bs, bc; sincospif(-ty * (float)(2 * hi - 64) * (1.0f / 64.0f), &bs, &bc);
            float qs4, qc4; sincospif(-ty * 0.0625f,   &qs4, &qc4);  // y += 4
            float os1, oc1; sincospif(-ty * 0.015625f, &os1, &oc1);  // y += 1
            float rc = bc, rs = bs;
            #pragma unroll
            for (int q = 0; q < 4; ++q) {
                cb[2 * q] = rc;  sb[2 * q] = rs;
                cb[2 * q + 1] = rc * oc1 - rs * os1;
                sb[2 * q + 1] = fmaf(rc, os1, rs * oc1);
                if (q < 3) {
                    float tz = rc * qc4 - rs * qs4;
                    rs = fmaf(rc, qs4, rs * qc4);
                    rc = tz;
                }
            }
        }

        // ---- ct loop: 8 blocks of 32 ycols (16 y) each
        #pragma unroll 1
        for (int ct = 0; ct < 8; ++ct) {
            const int off = 8192 * ct + 128 * P;
            bf16x8 f0 = *(const bf16x8*)(B0 + off);
            bf16x8 f1 = *(const bf16x8*)(B1 + off);
            bf16x8 f2 = *(const bf16x8*)(B2 + off);
            bf16x8 f3 = *(const bf16x8*)(B3 + off);
            f32x16 a1, a2;
            __builtin_amdgcn_s_setprio(1);
            a1 = __builtin_amdgcn_mfma_f32_32x32x16_bf16(f0, pxr[0], ZER16, 0,0,0);
            a2 = __builtin_amdgcn_mfma_f32_32x32x16_bf16(f0, pxi[0], ZER16, 0,0,0);
            a1 = __builtin_amdgcn_mfma_f32_32x32x16_bf16(f1, pxr[1], a1,    0,0,0);
            a2 = __builtin_amdgcn_mfma_f32_32x32x16_bf16(f1, pxi[1], a2,    0,0,0);
            a1 = __builtin_amdgcn_mfma_f32_32x32x16_bf16(f2, pxr[2], a1,    0,0,0);
            a2 = __builtin_amdgcn_mfma_f32_32x32x16_bf16(f2, pxi[2], a2,    0,0,0);
            a1 = __builtin_amdgcn_mfma_f32_32x32x16_bf16(f3, pxr[3], a1,    0,0,0);
            a2 = __builtin_amdgcn_mfma_f32_32x32x16_bf16(f3, pxi[3], a2,    0,0,0);
            __builtin_amdgcn_s_setprio(0);
            // stage 2: rows 4q+2j (re) / 4q+2j+1 (im) -> S(k,y); out += S*Py
            #pragma unroll
            for (int q = 0; q < 4; ++q) {
                #pragma unroll
                for (int j = 0; j < 2; ++j) {
                    const int e = 4 * q + 2 * j;
                    const int p = 2 * q + j;
                    float Sre = a1[e]     - a2[e + 1];
                    float Sim = a1[e + 1] + a2[e];
                    ore = fmaf(Sre,  cb[p], ore);
                    ore = fmaf(-Sim, sb[p], ore);
                    oim = fmaf(Sre,  sb[p], oim);
                    oim = fmaf(Sim,  cb[p], oim);
                }
            }
            // advance all 8 rotors by y += 16
            #pragma unroll
            for (int p = 0; p < 8; ++p) {
                float tz = cb[p] * rdr - sb[p] * rdi;
                sb[p] = fmaf(cb[p], rdi, sb[p] * rdr);
                cb[p] = tz;
            }
        }
    }

    // ---- epilogue: combine the two x/y半 halves held by lanes l and l+32
    float rre = ore + __shfl_xor(ore, 32);
    float rim = oim + __shfl_xor(oim, 32);
    if (lane < 32) {
        out[(size_t)c * KPTS + k]                      = rre;
        out[(size_t)NCH * KPTS + (size_t)c * KPTS + k] = rim;
    }
}

extern "C" void kernel_launch(void* const* d_in, const int* in_sizes, int n_in,
                              void* d_out, int out_size, void* d_ws, size_t ws_size,
                              hipStream_t stream)
{
    const float* img_real = (const float*)d_in[0];  // (8,128,128) fp32
    const float* img_imag = (const float*)d_in[1];  // (8,128,128) fp32
    const float* trj      = (const float*)d_in[2];  // (16384,2) fp32
    float* out = (float*)d_out;                      // planar: re block then im block
    unsigned short* B_pre = (unsigned short*)d_ws;   // 512 KB bf16 pre-swizzled img

    prep_kernel<<<128, 256, 0, stream>>>(img_real, img_imag, B_pre);
    nudft_mfma_kernel<<<dim3(64, 8), 512, 0, stream>>>(trj, B_pre, out);
}